// Round 9
// baseline (6405.151 us; speedup 1.0000x reference)
//
#include <hip/hip_runtime.h>
#include <math.h>

#define BB 256
#define TT 128
#define NN 512
#define HH 512
#define G3 1536
#define SLAB (HH * BB)     // 131072
#define XSLAB (G3 * BB)    // 393216
#define NPB 256            // persistent blocks
#define LDSB 160512        // 147456 (whi) + 13056 (scr)

typedef __attribute__((ext_vector_type(8))) short bf16x8;
typedef __attribute__((ext_vector_type(4))) float f32x4;
typedef unsigned short ushort;

struct PB {
    const float* x;
    const float* bih0; const float* bhh0; const float* bih1; const float* bhh1;
    ushort *W0ih_h, *W0ih_l, *Whh0_h, *Whh0_l;
    ushort *Wih1_h, *Wih1_l, *Whh1_h, *Whh1_l;
    float *xi0, *xi1, *h0f, *h1f;
    ushort *H0h, *H0l, *H1h, *H1l;
    unsigned *bcnt, *bgen;
};

__device__ __forceinline__ ushort bf16_rne(float f) {
    union { float f; unsigned u; } v; v.f = f;
    unsigned r = (v.u + 0x7fffu + ((v.u >> 16) & 1u)) >> 16;
    return (ushort)r;
}
__device__ __forceinline__ float bf16_tof(ushort h) {
    union { float f; unsigned u; } v; v.u = ((unsigned)h) << 16;
    return v.f;
}
__device__ __forceinline__ float sigm(float v) { return 1.f / (1.f + expf(-v)); }

__device__ __forceinline__ void split8(float4 a, float4 b, uint4& hi, uint4& lo) {
    float f[8] = {a.x, a.y, a.z, a.w, b.x, b.y, b.z, b.w};
    ushort hs[8], ls[8];
#pragma unroll
    for (int q = 0; q < 8; ++q) {
        ushort h = bf16_rne(f[q]);
        hs[q] = h;
        ls[q] = bf16_rne(f[q] - bf16_tof(h));
    }
    hi = *(uint4*)hs;
    lo = *(uint4*)ls;
}

__global__ void zero_kernel(float* p, int n) {
    int i = blockIdx.x * blockDim.x + threadIdx.x;
    if (i < n) p[i] = 0.f;
}

__global__ __launch_bounds__(256) void convert_split(
    const float* __restrict__ in, ushort* __restrict__ hi,
    ushort* __restrict__ lo, int n) {
    int i = (blockIdx.x * 256 + threadIdx.x) * 4;
    if (i >= n) return;
    float4 v = *(const float4*)(in + i);
    float f[4] = {v.x, v.y, v.z, v.w};
    ushort h[4], l[4];
#pragma unroll
    for (int q = 0; q < 4; ++q) {
        ushort hh = bf16_rne(f[q]);
        h[q] = hh;
        l[q] = bf16_rne(f[q] - bf16_tof(hh));
    }
    *(ushort4*)(hi + i) = *(ushort4*)h;
    *(ushort4*)(lo + i) = *(ushort4*)l;
}

// ---- persistent-kernel building blocks -------------------------------------

// 3-gate GEMM core over one k-quarter: A = 48-row panel (hi from LDS or global,
// lo streamed), B = bf16 hi/lo rows [b][512].
template <bool USELDS>
__device__ __forceinline__ void core3(
    const ushort* __restrict__ whiLds, const ushort* __restrict__ hiG,
    const ushort* __restrict__ loG, int jt,
    const ushort* __restrict__ Bh, const ushort* __restrict__ Bl,
    int b0, int kq, int ct, int l15, int l4, f32x4 acc[3]) {
    const int brow = b0 + ct * 16 + l15;
    const ushort* bhp = Bh + (size_t)brow * 512 + kq * 128 + l4 * 8;
    const ushort* blp = Bl + (size_t)brow * 512 + kq * 128 + l4 * 8;
#pragma unroll
    for (int it = 0; it < 4; ++it) {
        const int kof = it * 32;
        bf16x8 bh = *(const bf16x8*)(bhp + kof);
        bf16x8 bl = *(const bf16x8*)(blp + kof);
        const int k = kq * 128 + kof + l4 * 8;
#pragma unroll
        for (int g = 0; g < 3; ++g) {
            bf16x8 ah;
            if (USELDS) {
                const int r = g * 16 + l15;
                const int idx = (r * 512 + k) ^ ((r & 7) << 3);
                ah = *(const bf16x8*)(whiLds + idx);
            } else {
                const int grow = g * 512 + jt * 16 + l15;
                ah = *(const bf16x8*)(hiG + (size_t)grow * 512 + k);
            }
            const int grow = g * 512 + jt * 16 + l15;
            bf16x8 al = *(const bf16x8*)(loG + (size_t)grow * 512 + k);
            acc[g] = __builtin_amdgcn_mfma_f32_16x16x32_bf16(ah, bh, acc[g], 0, 0, 0);
            acc[g] = __builtin_amdgcn_mfma_f32_16x16x32_bf16(ah, bl, acc[g], 0, 0, 0);
            acc[g] = __builtin_amdgcn_mfma_f32_16x16x32_bf16(al, bh, acc[g], 0, 0, 0);
        }
    }
}

// cross-k-quarter reduction via LDS scratch (4 slots x 3 gates x 16j x 17-pad)
__device__ __forceinline__ void kreduce(float* scr, int kq, int ct, int l15, int l4,
                                        f32x4 acc[3]) {
    const int slot = (kq >> 1) * 2 + ct;
    const int pos0 = (l4 * 4) * 17 + l15;
    __syncthreads();
    if (kq & 1) {
#pragma unroll
        for (int g = 0; g < 3; ++g)
#pragma unroll
            for (int q = 0; q < 4; ++q)
                scr[slot * 816 + g * 272 + pos0 + q * 17] = acc[g][q];
    }
    __syncthreads();
    if (!(kq & 1)) {
#pragma unroll
        for (int g = 0; g < 3; ++g)
#pragma unroll
            for (int q = 0; q < 4; ++q)
                acc[g][q] += scr[slot * 816 + g * 272 + pos0 + q * 17];
    }
    if (kq == 2) {
#pragma unroll
        for (int g = 0; g < 3; ++g)
#pragma unroll
            for (int q = 0; q < 4; ++q)
                scr[(2 + ct) * 816 + g * 272 + pos0 + q * 17] = acc[g][q];
    }
    __syncthreads();
    if (kq == 0) {
#pragma unroll
        for (int g = 0; g < 3; ++g)
#pragma unroll
            for (int q = 0; q < 4; ++q)
                acc[g][q] += scr[(2 + ct) * 816 + g * 272 + pos0 + q * 17];
    }
}

__device__ __forceinline__ void epi_xi(float* __restrict__ xo,
    const float* __restrict__ bias, int jt, int b0, int kq, int ct, int l15, int l4,
    const f32x4 acc[3]) {
    if (kq != 0) return;
    const int b = b0 + ct * 16 + l15;
#pragma unroll
    for (int g = 0; g < 3; ++g)
#pragma unroll
        for (int q = 0; q < 4; ++q) {
            int grow = g * 512 + jt * 16 + l4 * 4 + q;
            xo[(size_t)grow * 256 + b] = acc[g][q] + bias[grow];
        }
}

__device__ __forceinline__ void epi_gru(const float* __restrict__ xi,
    const float* __restrict__ bhh, const float* __restrict__ hpv,
    float* __restrict__ hnew, ushort* __restrict__ Hh, ushort* __restrict__ Hl,
    int jt, int b0, int kq, int ct, int l15, int l4, const f32x4 acc[3]) {
    if (kq != 0) return;
    const int b = b0 + ct * 16 + l15;
    ushort hq[4], lq[4];
#pragma unroll
    for (int q = 0; q < 4; ++q) {
        int jrow = jt * 16 + l4 * 4 + q;
        float xr = xi[(size_t)jrow * 256 + b];
        float xz = xi[(size_t)(512 + jrow) * 256 + b];
        float xn = xi[(size_t)(1024 + jrow) * 256 + b];
        float hp = hpv[(size_t)jrow * 256 + b];
        float rr = sigm(xr + acc[0][q] + bhh[jrow]);
        float zz = sigm(xz + acc[1][q] + bhh[512 + jrow]);
        float nn = tanhf(xn + rr * (acc[2][q] + bhh[1024 + jrow]));
        float hv = (1.f - zz) * nn + zz * hp;
        hnew[(size_t)jrow * 256 + b] = hv;
        ushort hh = bf16_rne(hv);
        hq[q] = hh;
        lq[q] = bf16_rne(hv - bf16_tof(hh));
    }
    size_t o = (size_t)b * 512 + jt * 16 + l4 * 4;
    *(ushort4*)(Hh + o) = *(ushort4*)hq;
    *(ushort4*)(Hl + o) = *(ushort4*)lq;
}

// one pipelined step: xi0-phase (every 8), L0(t=s), XI1(t=s-1), L1(t=s-2)
template <bool USELDS>
__device__ __forceinline__ void step_body(int s, const PB& a, const ushort* whi,
    float* scr, int jt, int b0, int kq, int ct, int l15, int l4) {
    if ((s & 7) == 0 && s < 128) {        // xi0 phase: t in [s, s+8)
        for (int tt = s; tt < s + 8; ++tt) {
            f32x4 acc[3] = {};
            const int brow = b0 + ct * 16 + l15;
            const float* xb = a.x + ((size_t)brow * TT + tt) * NN;
#pragma unroll
            for (int it = 0; it < 4; ++it) {
                const int k = kq * 128 + it * 32 + l4 * 8;
                float4 f0 = *(const float4*)(xb + k);
                float4 f1 = *(const float4*)(xb + k + 4);
                uint4 bhv, blv;
                split8(f0, f1, bhv, blv);
                bf16x8 bh = *(bf16x8*)&bhv, bl = *(bf16x8*)&blv;
#pragma unroll
                for (int g = 0; g < 3; ++g) {
                    int grow = g * 512 + jt * 16 + l15;
                    bf16x8 ah = *(const bf16x8*)(a.W0ih_h + (size_t)grow * 512 + k);
                    bf16x8 al = *(const bf16x8*)(a.W0ih_l + (size_t)grow * 512 + k);
                    acc[g] = __builtin_amdgcn_mfma_f32_16x16x32_bf16(ah, bh, acc[g], 0, 0, 0);
                    acc[g] = __builtin_amdgcn_mfma_f32_16x16x32_bf16(ah, bl, acc[g], 0, 0, 0);
                    acc[g] = __builtin_amdgcn_mfma_f32_16x16x32_bf16(al, bh, acc[g], 0, 0, 0);
                }
            }
            kreduce(scr, kq, ct, l15, l4, acc);
            epi_xi(a.xi0 + (size_t)(tt & 7) * XSLAB, a.bih0, jt, b0, kq, ct, l15, l4, acc);
        }
    }
    if (s <= 127) {                        // L0: t = s
        f32x4 acc[3] = {};
        core3<USELDS>(whi, a.Whh0_h, a.Whh0_l, jt,
                      a.H0h + (size_t)((s - 1) & 1) * SLAB,
                      a.H0l + (size_t)((s - 1) & 1) * SLAB,
                      b0, kq, ct, l15, l4, acc);
        kreduce(scr, kq, ct, l15, l4, acc);
        epi_gru(a.xi0 + (size_t)(s & 7) * XSLAB, a.bhh0,
                a.h0f + (size_t)((s - 1) & 1) * SLAB, a.h0f + (size_t)(s & 1) * SLAB,
                a.H0h + (size_t)(s & 1) * SLAB, a.H0l + (size_t)(s & 1) * SLAB,
                jt, b0, kq, ct, l15, l4, acc);
    }
    if (s >= 1 && s <= 128) {              // XI1: t = s-1
        const int t = s - 1;
        f32x4 acc[3] = {};
        core3<USELDS>(whi + 24576, a.Wih1_h, a.Wih1_l, jt,
                      a.H0h + (size_t)(t & 1) * SLAB, a.H0l + (size_t)(t & 1) * SLAB,
                      b0, kq, ct, l15, l4, acc);
        kreduce(scr, kq, ct, l15, l4, acc);
        epi_xi(a.xi1 + (size_t)(t & 1) * XSLAB, a.bih1, jt, b0, kq, ct, l15, l4, acc);
    }
    if (s >= 2) {                          // L1: t = s-2
        const int t = s - 2;
        f32x4 acc[3] = {};
        core3<USELDS>(whi + 49152, a.Whh1_h, a.Whh1_l, jt,
                      a.H1h + (size_t)((t - 1) & 1) * SLAB,
                      a.H1l + (size_t)((t - 1) & 1) * SLAB,
                      b0, kq, ct, l15, l4, acc);
        kreduce(scr, kq, ct, l15, l4, acc);
        epi_gru(a.xi1 + (size_t)(t & 1) * XSLAB, a.bhh1,
                a.h1f + (size_t)((t - 1) & 1) * SLAB, a.h1f + (size_t)(t & 1) * SLAB,
                a.H1h + (size_t)(t & 1) * SLAB, a.H1l + (size_t)(t & 1) * SLAB,
                jt, b0, kq, ct, l15, l4, acc);
    }
}

__device__ __forceinline__ void gbar(unsigned* cnt, unsigned* gen, unsigned& mygen) {
    __syncthreads();
    if (threadIdx.x == 0) {
        __threadfence();
        unsigned old = atomicAdd(cnt, 1u);
        if (old == NPB - 1) {
            atomicExch(cnt, 0u);
            __threadfence();
            atomicAdd(gen, 1u);
        } else {
            while (__hip_atomic_load(gen, __ATOMIC_RELAXED, __HIP_MEMORY_SCOPE_AGENT)
                   <= mygen)
                __builtin_amdgcn_s_sleep(2);
        }
        __threadfence();
    }
    __syncthreads();
    ++mygen;
}

__global__ __launch_bounds__(512, 1) void gru_persist(PB a) {
    extern __shared__ ushort ldsbuf[];
    ushort* whi = ldsbuf;                       // [3][48][512] swizzled
    float* scr = (float*)(ldsbuf + 73728);      // 3264 floats
    const int bi = blockIdx.x;
    const int jt = (bi & 7) * 4 + ((bi >> 3) & 3);
    const int b0 = (bi >> 5) * 32;
    const int tid = threadIdx.x, w = tid >> 6, lane = tid & 63;
    const int l15 = lane & 15, l4 = lane >> 4;
    const int kq = w >> 1, ct = w & 1;

    {   // load hi-weights into LDS (swizzled)
        const ushort* srcs[3] = {a.Whh0_h, a.Wih1_h, a.Whh1_h};
        for (int u = tid; u < 3 * 48 * 64; u += 512) {
            int k8 = u & 63, r = (u >> 6) % 48, sec = u / 3072;
            int grow = (r >> 4) * 512 + jt * 16 + (r & 15);
            uint4 v = *(const uint4*)(srcs[sec] + (size_t)grow * 512 + k8 * 8);
            int idx = (sec * 24576 + r * 512 + k8 * 8) ^ ((r & 7) << 3);
            *(uint4*)(whi + idx) = v;
        }
    }
    {   // zero initial-state slices (slot 1)
        int j = tid >> 5, b = tid & 31;
        size_t o = (size_t)SLAB + (size_t)(jt * 16 + j) * 256 + b0 + b;
        a.h0f[o] = 0.f;
        a.h1f[o] = 0.f;
        int bb = b0 + (tid >> 4), cc = jt * 16 + (tid & 15);
        size_t o2 = (size_t)SLAB + (size_t)bb * 512 + cc;
        a.H0h[o2] = 0; a.H0l[o2] = 0; a.H1h[o2] = 0; a.H1l[o2] = 0;
    }
    unsigned mygen = 0;
    gbar(a.bcnt, a.bgen, mygen);
    for (int s = 0; s <= 129; ++s) {
        step_body<true>(s, a, whi, scr, jt, b0, kq, ct, l15, l4);
        gbar(a.bcnt, a.bgen, mygen);
    }
}

// fallback: one step per launch, weights fully streamed
__global__ __launch_bounds__(512) void step_np(int s, PB a) {
    __shared__ float scr[3264];
    const int bi = blockIdx.x;
    const int jt = (bi & 7) * 4 + ((bi >> 3) & 3);
    const int b0 = (bi >> 5) * 32;
    const int tid = threadIdx.x, w = tid >> 6, lane = tid & 63;
    const int l15 = lane & 15, l4 = lane >> 4;
    step_body<false>(s, a, nullptr, scr, jt, b0, w >> 1, w & 1, l15, l4);
}

// ---- tail ------------------------------------------------------------------

__global__ __launch_bounds__(256) void hT_to_h(
    const float* __restrict__ hT, float* __restrict__ h) {
    __shared__ float tb[64][65];
    const int tid = threadIdx.x;
    const int k0 = blockIdx.x * 64, b0 = blockIdx.y * 64;
#pragma unroll
    for (int i = 0; i < 4; ++i) {
        int r = (tid >> 4) + 16 * i, c = (tid & 15) * 4;
        float4 v = *(const float4*)(hT + (size_t)(k0 + r) * 256 + b0 + c);
        tb[c + 0][r] = v.x; tb[c + 1][r] = v.y; tb[c + 2][r] = v.z; tb[c + 3][r] = v.w;
    }
    __syncthreads();
#pragma unroll
    for (int i = 0; i < 4; ++i) {
        int r = (tid >> 4) + 16 * i, c = (tid & 15) * 4;
        float4 v;
        v.x = tb[r][c]; v.y = tb[r][c + 1]; v.z = tb[r][c + 2]; v.w = tb[r][c + 3];
        *(float4*)(h + (size_t)(b0 + r) * 512 + k0 + c) = v;
    }
}

__device__ __forceinline__ float blockReduceSum(float v, float* tmp) {
    __syncthreads();
#pragma unroll
    for (int o = 32; o; o >>= 1) v += __shfl_down(v, o);
    if ((threadIdx.x & 63) == 0) tmp[threadIdx.x >> 6] = v;
    __syncthreads();
    if (threadIdx.x == 0) tmp[4] = tmp[0] + tmp[1] + tmp[2] + tmp[3];
    __syncthreads();
    return tmp[4];
}

__device__ __forceinline__ float blockReduceMax(float v, float* tmp) {
    __syncthreads();
#pragma unroll
    for (int o = 32; o; o >>= 1) v = fmaxf(v, __shfl_down(v, o));
    if ((threadIdx.x & 63) == 0) tmp[threadIdx.x >> 6] = v;
    __syncthreads();
    if (threadIdx.x == 0) tmp[4] = fmaxf(fmaxf(tmp[0], tmp[1]), fmaxf(tmp[2], tmp[3]));
    __syncthreads();
    return tmp[4];
}

__global__ __launch_bounds__(256) void head_kernel(
    const float* __restrict__ h1, const float* __restrict__ fcw,
    const float* __restrict__ fcb, float* __restrict__ out) {
    __shared__ __align__(16) float hrow[512];
    __shared__ float wv[512];
    __shared__ float ov[512];
    __shared__ float tmp[8];
    const int b = blockIdx.x, tid = threadIdx.x;
    hrow[tid]       = h1[(size_t)b * 512 + tid];
    hrow[tid + 256] = h1[(size_t)b * 512 + 256 + tid];
    __syncthreads();

    float s[2];
#pragma unroll
    for (int q = 0; q < 2; ++q) {
        int n = tid + q * 256;
        const float* wr = fcw + (size_t)n * 512;
        float acc = 0.f;
        for (int k = 0; k < 512; k += 4) {
            float4 wq = *(const float4*)(wr + k);
            acc += wq.x * hrow[k] + wq.y * hrow[k + 1] + wq.z * hrow[k + 2] + wq.w * hrow[k + 3];
        }
        float l = acc + fcb[n];
        s[q] = l / (1.f + expf(-l));
    }

    float mx = blockReduceMax(fmaxf(s[0], s[1]), tmp);
    float e0 = expf(s[0] - mx), e1 = expf(s[1] - mx);
    float sum = blockReduceSum(e0 + e1, tmp);
    float w0 = e0 / sum, w1 = e1 / sum;

    ov[tid] = w0;       ov[tid + 256] = w1;
    wv[tid]       = fminf(fmaxf(w0, 0.f), 0.1f);
    wv[tid + 256] = fminf(fmaxf(w1, 0.f), 0.1f);
    __syncthreads();

    for (int it = 0; it < 32; ++it) {
        float wc0 = wv[tid], wc1 = wv[tid + 256];
        float o0 = ov[tid], o1 = ov[tid + 256];
        float leftover = blockReduceSum((o0 - wc0) + (o1 - wc1), tmp);
        float n0 = (wc0 != 0.1f) ? wc0 : 0.f;
        float n1 = (wc1 != 0.1f) ? wc1 : 0.f;
        float denom = blockReduceSum(n0 + n1, tmp);
        float w20 = wc0 + leftover * n0 / denom;
        float w21 = wc1 + leftover * n1 / denom;
        float fl = ((w20 > 0.1f) || (w21 > 0.1f)) ? 1.f : 0.f;
        bool again = blockReduceSum(fl, tmp) > 0.f;
        __syncthreads();
        ov[tid] = w20; ov[tid + 256] = w21;
        wv[tid]       = again ? fminf(fmaxf(w20, 0.f), 0.1f) : w20;
        wv[tid + 256] = again ? fminf(fmaxf(w21, 0.f), 0.1f) : w21;
        __syncthreads();
        if (!again) break;
    }

    out[(size_t)b * 512 + tid]       = wv[tid];
    out[(size_t)b * 512 + 256 + tid] = wv[tid + 256];
}

extern "C" void kernel_launch(void* const* d_in, const int* in_sizes, int n_in,
                              void* d_out, int out_size, void* d_ws, size_t ws_size,
                              hipStream_t stream) {
    const float* x    = (const float*)d_in[0];
    const float* Wih0 = (const float*)d_in[1];
    const float* Whh0 = (const float*)d_in[2];
    const float* bih0 = (const float*)d_in[3];
    const float* bhh0 = (const float*)d_in[4];
    const float* Wih1 = (const float*)d_in[5];
    const float* Whh1 = (const float*)d_in[6];
    const float* bih1 = (const float*)d_in[7];
    const float* bhh1 = (const float*)d_in[8];
    const float* fcw  = (const float*)d_in[9];
    const float* fcb  = (const float*)d_in[10];
    float* out = (float*)d_out;

    PB a;
    a.x = x; a.bih0 = bih0; a.bhh0 = bhh0; a.bih1 = bih1; a.bhh1 = bhh1;
    unsigned* bar = (unsigned*)d_ws;
    a.bcnt = bar; a.bgen = bar + 1;
    ushort* w16 = (ushort*)((char*)d_ws + 256);
    const size_t WHALF = (size_t)G3 * HH;   // 786432
    a.W0ih_h = w16;              a.W0ih_l = a.W0ih_h + WHALF;
    a.Whh0_h = a.W0ih_l + WHALF; a.Whh0_l = a.Whh0_h + WHALF;
    a.Wih1_h = a.Whh0_l + WHALF; a.Wih1_l = a.Wih1_h + WHALF;
    a.Whh1_h = a.Wih1_l + WHALF; a.Whh1_l = a.Whh1_h + WHALF;
    float* f32p = (float*)(a.Whh1_l + WHALF);
    a.xi0 = f32p;                f32p += 8 * (size_t)XSLAB;
    a.xi1 = f32p;                f32p += 2 * (size_t)XSLAB;
    a.h0f = f32p;                f32p += 2 * (size_t)SLAB;
    a.h1f = f32p;                f32p += 2 * (size_t)SLAB;
    float* h1n = f32p;           f32p += (size_t)SLAB;
    ushort* h16 = (ushort*)f32p;
    a.H0h = h16;                 h16 += 2 * (size_t)SLAB;
    a.H0l = h16;                 h16 += 2 * (size_t)SLAB;
    a.H1h = h16;                 h16 += 2 * (size_t)SLAB;
    a.H1l = h16;

    const int wn = G3 * HH;
    convert_split<<<wn / 1024, 256, 0, stream>>>(Wih0, a.W0ih_h, a.W0ih_l, wn);
    convert_split<<<wn / 1024, 256, 0, stream>>>(Whh0, a.Whh0_h, a.Whh0_l, wn);
    convert_split<<<wn / 1024, 256, 0, stream>>>(Wih1, a.Wih1_h, a.Wih1_l, wn);
    convert_split<<<wn / 1024, 256, 0, stream>>>(Whh1, a.Whh1_h, a.Whh1_l, wn);
    hipMemsetAsync(d_ws, 0, 256, stream);

    hipError_t e = hipFuncSetAttribute(
        reinterpret_cast<const void*>(gru_persist),
        hipFuncAttributeMaxDynamicSharedMemorySize, LDSB);
    if (e == hipSuccess) {
        void* kargs[] = {(void*)&a};
        e = hipLaunchCooperativeKernel(gru_persist, dim3(NPB), dim3(512), kargs,
                                       (unsigned)LDSB, stream);
    }
    if (e != hipSuccess) {
        // fallback: per-step launches, weights streamed
        zero_kernel<<<SLAB / 256, 256, 0, stream>>>(a.h0f + SLAB, SLAB);
        zero_kernel<<<SLAB / 256, 256, 0, stream>>>(a.h1f + SLAB, SLAB);
        zero_kernel<<<(SLAB / 2) / 256, 256, 0, stream>>>((float*)(a.H0h + SLAB), SLAB / 2);
        zero_kernel<<<(SLAB / 2) / 256, 256, 0, stream>>>((float*)(a.H0l + SLAB), SLAB / 2);
        zero_kernel<<<(SLAB / 2) / 256, 256, 0, stream>>>((float*)(a.H1h + SLAB), SLAB / 2);
        zero_kernel<<<(SLAB / 2) / 256, 256, 0, stream>>>((float*)(a.H1l + SLAB), SLAB / 2);
        for (int s = 0; s <= 129; ++s)
            step_np<<<NPB, 512, 0, stream>>>(s, a);
    }

    hT_to_h<<<dim3(8, 4), 256, 0, stream>>>(a.h1f + SLAB, h1n);
    head_kernel<<<BB, 256, 0, stream>>>(h1n, fcw, fcb, out);
}

// Round 10
// 2164.910 us; speedup vs baseline: 2.9586x; 2.9586x over previous
//
#include <hip/hip_runtime.h>
#include <math.h>

#define BB 256
#define TT 128
#define NN 512
#define HH 512
#define G3 1536
#define SLAB (HH * BB)     // 131072
#define XSLAB (G3 * BB)    // 393216
#define CH 16

typedef __attribute__((ext_vector_type(8))) short bf16x8;
typedef __attribute__((ext_vector_type(4))) float f32x4;
typedef unsigned short ushort;

__device__ __forceinline__ ushort bf16_rne(float f) {
    union { float f; unsigned u; } v; v.f = f;
    unsigned r = (v.u + 0x7fffu + ((v.u >> 16) & 1u)) >> 16;
    return (ushort)r;
}
__device__ __forceinline__ float bf16_tof(ushort h) {
    union { float f; unsigned u; } v; v.u = ((unsigned)h) << 16;
    return v.f;
}
__device__ __forceinline__ float sigm(float v) { return 1.f / (1.f + expf(-v)); }

__global__ void zero_kernel(float* p, int n) {
    int i = blockIdx.x * blockDim.x + threadIdx.x;
    if (i < n) p[i] = 0.f;
}

__global__ __launch_bounds__(256) void convert_split(
    const float* __restrict__ in, ushort* __restrict__ hi,
    ushort* __restrict__ lo, int n) {
    int i = (blockIdx.x * 256 + threadIdx.x) * 4;
    if (i >= n) return;
    float4 v = *(const float4*)(in + i);
    float f[4] = {v.x, v.y, v.z, v.w};
    ushort h[4], l[4];
#pragma unroll
    for (int q = 0; q < 4; ++q) {
        ushort hh = bf16_rne(f[q]);
        h[q] = hh;
        l[q] = bf16_rne(f[q] - bf16_tof(hh));
    }
    *(ushort4*)(hi + i) = *(ushort4*)h;
    *(ushort4*)(lo + i) = *(ushort4*)l;
}

// One-time: pack Whh0/Wih1/Whh1 into per-lane MFMA fragment order.
// Record (sec,p,kq,it,g): 1024 ushorts = [hi: lane*8..+8 | lo at +512].
// value(lane,e) = split(W[g*512 + p*16 + (lane&15)][kq*128 + it*32 + (lane>>4)*8 + e])
__global__ __launch_bounds__(64) void pack_swz(
    const float* __restrict__ Whh0, const float* __restrict__ Wih1,
    const float* __restrict__ Whh1, ushort* __restrict__ pk) {
    const int bi = blockIdx.x;                 // (((sec*32+p)*4+kq)*4+it)
    const int it = bi & 3, kq = (bi >> 2) & 3, p = (bi >> 4) & 31, sec = bi >> 9;
    const float* W = (sec == 0) ? Whh0 : (sec == 1) ? Wih1 : Whh1;
    const int lane = threadIdx.x;
    const int l15 = lane & 15, l4 = lane >> 4;
    ushort* base = pk + (size_t)bi * 3072 + lane * 8;
#pragma unroll
    for (int g = 0; g < 3; ++g) {
        int grow = g * 512 + p * 16 + l15;
        const float* src = W + (size_t)grow * 512 + kq * 128 + it * 32 + l4 * 8;
        ushort hs[8], ls[8];
#pragma unroll
        for (int e = 0; e < 8; ++e) {
            float v = src[e];
            ushort h = bf16_rne(v);
            hs[e] = h;
            ls[e] = bf16_rne(v - bf16_tof(h));
        }
        *(uint4*)(base + g * 1024) = *(uint4*)hs;
        *(uint4*)(base + g * 1024 + 512) = *(uint4*)ls;
    }
}

// xi0 chunk GEMM (r7/r8, proven)
__global__ __launch_bounds__(256) void xi_mfma_x(
    const ushort* __restrict__ Wh, const ushort* __restrict__ Wl,
    const float* __restrict__ x, int t0,
    const float* __restrict__ bias, float* __restrict__ out) {
    __shared__ ushort As[2][128][40];
    __shared__ ushort Bs[2][128][40];
    const int tid = threadIdx.x;
    const int n0 = blockIdx.x * 128;
    const int g0 = blockIdx.y * 128;
    const int tl = n0 >> 8, b0 = n0 & 255;
    const int tg = t0 + tl;
    const int w = tid >> 6, lane = tid & 63;
    const int wg = (w >> 1) * 64, wb = (w & 1) * 64;
    const int l15 = lane & 15, l4 = lane >> 4;
    const int sr = tid >> 2, sc = (tid & 3) * 8;

    f32x4 acc[4][4] = {};
    for (int kc = 0; kc < 512; kc += 32) {
        uint4 a0 = *(const uint4*)(Wh + (size_t)(g0 + sr) * 512 + kc + sc);
        uint4 a1 = *(const uint4*)(Wh + (size_t)(g0 + 64 + sr) * 512 + kc + sc);
        uint4 a2 = *(const uint4*)(Wl + (size_t)(g0 + sr) * 512 + kc + sc);
        uint4 a3 = *(const uint4*)(Wl + (size_t)(g0 + 64 + sr) * 512 + kc + sc);
        const float* xr0 = x + ((size_t)(b0 + sr) * TT + tg) * NN + kc + sc;
        const float* xr1 = x + ((size_t)(b0 + 64 + sr) * TT + tg) * NN + kc + sc;
        float4 f00 = *(const float4*)xr0, f01 = *(const float4*)(xr0 + 4);
        float4 f10 = *(const float4*)xr1, f11 = *(const float4*)(xr1 + 4);
        float fa[8] = {f00.x, f00.y, f00.z, f00.w, f01.x, f01.y, f01.z, f01.w};
        float fb[8] = {f10.x, f10.y, f10.z, f10.w, f11.x, f11.y, f11.z, f11.w};
        ushort h0v[8], l0v[8], h1v[8], l1v[8];
#pragma unroll
        for (int q = 0; q < 8; ++q) {
            ushort hh = bf16_rne(fa[q]);
            h0v[q] = hh; l0v[q] = bf16_rne(fa[q] - bf16_tof(hh));
            hh = bf16_rne(fb[q]);
            h1v[q] = hh; l1v[q] = bf16_rne(fb[q] - bf16_tof(hh));
        }
        __syncthreads();
        *(uint4*)&As[0][sr][sc] = a0;      *(uint4*)&As[0][64 + sr][sc] = a1;
        *(uint4*)&As[1][sr][sc] = a2;      *(uint4*)&As[1][64 + sr][sc] = a3;
        *(uint4*)&Bs[0][sr][sc] = *(uint4*)h0v;  *(uint4*)&Bs[0][64 + sr][sc] = *(uint4*)h1v;
        *(uint4*)&Bs[1][sr][sc] = *(uint4*)l0v;  *(uint4*)&Bs[1][64 + sr][sc] = *(uint4*)l1v;
        __syncthreads();
        bf16x8 ah[4], al[4], bh[4], bl[4];
#pragma unroll
        for (int i = 0; i < 4; ++i) {
            ah[i] = *(const bf16x8*)&As[0][wg + 16 * i + l15][l4 * 8];
            al[i] = *(const bf16x8*)&As[1][wg + 16 * i + l15][l4 * 8];
            bh[i] = *(const bf16x8*)&Bs[0][wb + 16 * i + l15][l4 * 8];
            bl[i] = *(const bf16x8*)&Bs[1][wb + 16 * i + l15][l4 * 8];
        }
#pragma unroll
        for (int i = 0; i < 4; ++i)
#pragma unroll
            for (int j = 0; j < 4; ++j) {
                acc[i][j] = __builtin_amdgcn_mfma_f32_16x16x32_bf16(ah[i], bh[j], acc[i][j], 0, 0, 0);
                acc[i][j] = __builtin_amdgcn_mfma_f32_16x16x32_bf16(ah[i], bl[j], acc[i][j], 0, 0, 0);
                acc[i][j] = __builtin_amdgcn_mfma_f32_16x16x32_bf16(al[i], bh[j], acc[i][j], 0, 0, 0);
            }
    }
    float* op = out + (size_t)tl * XSLAB;
#pragma unroll
    for (int i = 0; i < 4; ++i) {
        int gbase = g0 + wg + 16 * i + l4 * 4;
#pragma unroll
        for (int r = 0; r < 4; ++r) {
            float bv = bias[gbase + r];
#pragma unroll
            for (int j = 0; j < 4; ++j)
                op[(size_t)(gbase + r) * 256 + b0 + wb + 16 * j + l15] = acc[i][j][r] + bv;
        }
    }
}

// cross-k-quarter reduction via LDS (r9, validated)
__device__ __forceinline__ void kreduce(float* scr, int kq, int ct, int l15, int l4,
                                        f32x4 acc[3]) {
    const int slot = (kq >> 1) * 2 + ct;
    const int pos0 = (l4 * 4) * 17 + l15;
    __syncthreads();
    if (kq & 1) {
#pragma unroll
        for (int g = 0; g < 3; ++g)
#pragma unroll
            for (int q = 0; q < 4; ++q)
                scr[slot * 816 + g * 272 + pos0 + q * 17] = acc[g][q];
    }
    __syncthreads();
    if (!(kq & 1)) {
#pragma unroll
        for (int g = 0; g < 3; ++g)
#pragma unroll
            for (int q = 0; q < 4; ++q)
                acc[g][q] += scr[slot * 816 + g * 272 + pos0 + q * 17];
    }
    if (kq == 2) {
#pragma unroll
        for (int g = 0; g < 3; ++g)
#pragma unroll
            for (int q = 0; q < 4; ++q)
                scr[(2 + ct) * 816 + g * 272 + pos0 + q * 17] = acc[g][q];
    }
    __syncthreads();
    if (kq == 0) {
#pragma unroll
        for (int g = 0; g < 3; ++g)
#pragma unroll
            for (int q = 0; q < 4; ++q)
                acc[g][q] += scr[(2 + ct) * 816 + g * 272 + pos0 + q * 17];
    }
}

__device__ __forceinline__ void epi_xi(float* __restrict__ xo,
    const float* __restrict__ bias, int p, int b0, int kq, int ct, int l15, int l4,
    const f32x4 acc[3]) {
    if (kq != 0) return;
    const int b = b0 + ct * 16 + l15;
#pragma unroll
    for (int g = 0; g < 3; ++g)
#pragma unroll
        for (int q = 0; q < 4; ++q) {
            int grow = g * 512 + p * 16 + l4 * 4 + q;
            xo[(size_t)grow * 256 + b] = acc[g][q] + bias[grow];
        }
}

__device__ __forceinline__ void epi_gru(const float* __restrict__ xi,
    const float* __restrict__ bhh, const float* __restrict__ hpv,
    float* __restrict__ hnew, ushort* __restrict__ Hh, ushort* __restrict__ Hl,
    int p, int b0, int kq, int ct, int l15, int l4, const f32x4 acc[3]) {
    if (kq != 0) return;
    const int b = b0 + ct * 16 + l15;
    ushort hq[4], lq[4];
#pragma unroll
    for (int q = 0; q < 4; ++q) {
        int jrow = p * 16 + l4 * 4 + q;
        float xr = xi[(size_t)jrow * 256 + b];
        float xz = xi[(size_t)(512 + jrow) * 256 + b];
        float xn = xi[(size_t)(1024 + jrow) * 256 + b];
        float hp = hpv[(size_t)jrow * 256 + b];
        float rr = sigm(xr + acc[0][q] + bhh[jrow]);
        float zz = sigm(xz + acc[1][q] + bhh[512 + jrow]);
        float nn = tanhf(xn + rr * (acc[2][q] + bhh[1024 + jrow]));
        float hv = (1.f - zz) * nn + zz * hp;
        hnew[(size_t)jrow * 256 + b] = hv;
        ushort hh = bf16_rne(hv);
        hq[q] = hh;
        lq[q] = bf16_rne(hv - bf16_tof(hh));
    }
    size_t o = (size_t)b * 512 + p * 16 + l4 * 4;
    *(ushort4*)(Hh + o) = *(ushort4*)hq;
    *(ushort4*)(Hl + o) = *(ushort4*)lq;
}

// Per-step kernel: no-staging streamed GEMM from pre-swizzled pk.
// sections: 0=L0(t=s) 1=XI1(t=s-1) 2=L1(t=s-2); 256 blocks each; 512 thr.
__global__ __launch_bounds__(512) void step_v10(
    int s, const ushort* __restrict__ pk,
    const float* __restrict__ xi0, float* __restrict__ xi1,
    const float* __restrict__ bih1,
    const float* __restrict__ bhh0, const float* __restrict__ bhh1,
    float* __restrict__ h0f, float* __restrict__ h1f,
    ushort* __restrict__ H0h, ushort* __restrict__ H0l,
    ushort* __restrict__ H1h, ushort* __restrict__ H1l) {
    __shared__ float scr[3264];
    const int bi = blockIdx.x;
    const int sec = bi >> 8, local = bi & 255;
    const int t = (sec == 0) ? s : (sec == 1) ? s - 1 : s - 2;
    if (t < 0 || t > 127) return;
    const int p = (local & 7) * 4 + ((local >> 3) & 3);   // panel, XCD-exclusive
    const int b0 = (local >> 5) * 32;
    const int tid = threadIdx.x, w = tid >> 6, lane = tid & 63;
    const int l15 = lane & 15, l4 = lane >> 4;
    const int kq = w >> 1, ct = w & 1;

    const ushort *Bh, *Bl;
    if (sec == 0)      { int sl = (t - 1) & 1; Bh = H0h + (size_t)sl * SLAB; Bl = H0l + (size_t)sl * SLAB; }
    else if (sec == 1) { int sl = t & 1;       Bh = H0h + (size_t)sl * SLAB; Bl = H0l + (size_t)sl * SLAB; }
    else               { int sl = (t - 1) & 1; Bh = H1h + (size_t)sl * SLAB; Bl = H1l + (size_t)sl * SLAB; }

    const ushort* baseA = pk + (size_t)((sec * 32 + p) * 4 + kq) * 12288 + lane * 8;
    const int brow = b0 + ct * 16 + l15;
    const ushort* bhp = Bh + (size_t)brow * 512 + kq * 128 + l4 * 8;
    const ushort* blp = Bl + (size_t)brow * 512 + kq * 128 + l4 * 8;

    f32x4 acc[3] = {};
#pragma unroll
    for (int it = 0; it < 4; ++it) {
        bf16x8 bh = *(const bf16x8*)(bhp + it * 32);
        bf16x8 bl = *(const bf16x8*)(blp + it * 32);
#pragma unroll
        for (int g = 0; g < 3; ++g) {
            const ushort* rec = baseA + (it * 3 + g) * 1024;
            bf16x8 ah = *(const bf16x8*)rec;
            bf16x8 al = *(const bf16x8*)(rec + 512);
            acc[g] = __builtin_amdgcn_mfma_f32_16x16x32_bf16(ah, bh, acc[g], 0, 0, 0);
            acc[g] = __builtin_amdgcn_mfma_f32_16x16x32_bf16(ah, bl, acc[g], 0, 0, 0);
            acc[g] = __builtin_amdgcn_mfma_f32_16x16x32_bf16(al, bh, acc[g], 0, 0, 0);
        }
    }
    kreduce(scr, kq, ct, l15, l4, acc);
    if (sec == 1) {
        epi_xi(xi1 + (size_t)(t & 1) * XSLAB, bih1, p, b0, kq, ct, l15, l4, acc);
    } else if (sec == 0) {
        epi_gru(xi0 + (size_t)(t & (CH - 1)) * XSLAB, bhh0,
                h0f + (size_t)((t - 1) & 1) * SLAB, h0f + (size_t)(t & 1) * SLAB,
                H0h + (size_t)(t & 1) * SLAB, H0l + (size_t)(t & 1) * SLAB,
                p, b0, kq, ct, l15, l4, acc);
    } else {
        epi_gru(xi1 + (size_t)(t & 1) * XSLAB, bhh1,
                h1f + (size_t)((t - 1) & 1) * SLAB, h1f + (size_t)(t & 1) * SLAB,
                H1h + (size_t)(t & 1) * SLAB, H1l + (size_t)(t & 1) * SLAB,
                p, b0, kq, ct, l15, l4, acc);
    }
}

// ---- tail ------------------------------------------------------------------

__global__ __launch_bounds__(256) void hT_to_h(
    const float* __restrict__ hT, float* __restrict__ h) {
    __shared__ float tb[64][65];
    const int tid = threadIdx.x;
    const int k0 = blockIdx.x * 64, b0 = blockIdx.y * 64;
#pragma unroll
    for (int i = 0; i < 4; ++i) {
        int r = (tid >> 4) + 16 * i, c = (tid & 15) * 4;
        float4 v = *(const float4*)(hT + (size_t)(k0 + r) * 256 + b0 + c);
        tb[c + 0][r] = v.x; tb[c + 1][r] = v.y; tb[c + 2][r] = v.z; tb[c + 3][r] = v.w;
    }
    __syncthreads();
#pragma unroll
    for (int i = 0; i < 4; ++i) {
        int r = (tid >> 4) + 16 * i, c = (tid & 15) * 4;
        float4 v;
        v.x = tb[r][c]; v.y = tb[r][c + 1]; v.z = tb[r][c + 2]; v.w = tb[r][c + 3];
        *(float4*)(h + (size_t)(b0 + r) * 512 + k0 + c) = v;
    }
}

__device__ __forceinline__ float blockReduceSum(float v, float* tmp) {
    __syncthreads();
#pragma unroll
    for (int o = 32; o; o >>= 1) v += __shfl_down(v, o);
    if ((threadIdx.x & 63) == 0) tmp[threadIdx.x >> 6] = v;
    __syncthreads();
    if (threadIdx.x == 0) tmp[4] = tmp[0] + tmp[1] + tmp[2] + tmp[3];
    __syncthreads();
    return tmp[4];
}

__device__ __forceinline__ float blockReduceMax(float v, float* tmp) {
    __syncthreads();
#pragma unroll
    for (int o = 32; o; o >>= 1) v = fmaxf(v, __shfl_down(v, o));
    if ((threadIdx.x & 63) == 0) tmp[threadIdx.x >> 6] = v;
    __syncthreads();
    if (threadIdx.x == 0) tmp[4] = fmaxf(fmaxf(tmp[0], tmp[1]), fmaxf(tmp[2], tmp[3]));
    __syncthreads();
    return tmp[4];
}

__global__ __launch_bounds__(256) void head_kernel(
    const float* __restrict__ h1, const float* __restrict__ fcw,
    const float* __restrict__ fcb, float* __restrict__ out) {
    __shared__ __align__(16) float hrow[512];
    __shared__ float wv[512];
    __shared__ float ov[512];
    __shared__ float tmp[8];
    const int b = blockIdx.x, tid = threadIdx.x;
    hrow[tid]       = h1[(size_t)b * 512 + tid];
    hrow[tid + 256] = h1[(size_t)b * 512 + 256 + tid];
    __syncthreads();

    float s[2];
#pragma unroll
    for (int q = 0; q < 2; ++q) {
        int n = tid + q * 256;
        const float* wr = fcw + (size_t)n * 512;
        float acc = 0.f;
        for (int k = 0; k < 512; k += 4) {
            float4 wq = *(const float4*)(wr + k);
            acc += wq.x * hrow[k] + wq.y * hrow[k + 1] + wq.z * hrow[k + 2] + wq.w * hrow[k + 3];
        }
        float l = acc + fcb[n];
        s[q] = l / (1.f + expf(-l));
    }

    float mx = blockReduceMax(fmaxf(s[0], s[1]), tmp);
    float e0 = expf(s[0] - mx), e1 = expf(s[1] - mx);
    float sum = blockReduceSum(e0 + e1, tmp);
    float w0 = e0 / sum, w1 = e1 / sum;

    ov[tid] = w0;       ov[tid + 256] = w1;
    wv[tid]       = fminf(fmaxf(w0, 0.f), 0.1f);
    wv[tid + 256] = fminf(fmaxf(w1, 0.f), 0.1f);
    __syncthreads();

    for (int it = 0; it < 32; ++it) {
        float wc0 = wv[tid], wc1 = wv[tid + 256];
        float o0 = ov[tid], o1 = ov[tid + 256];
        float leftover = blockReduceSum((o0 - wc0) + (o1 - wc1), tmp);
        float n0 = (wc0 != 0.1f) ? wc0 : 0.f;
        float n1 = (wc1 != 0.1f) ? wc1 : 0.f;
        float denom = blockReduceSum(n0 + n1, tmp);
        float w20 = wc0 + leftover * n0 / denom;
        float w21 = wc1 + leftover * n1 / denom;
        float fl = ((w20 > 0.1f) || (w21 > 0.1f)) ? 1.f : 0.f;
        bool again = blockReduceSum(fl, tmp) > 0.f;
        __syncthreads();
        ov[tid] = w20; ov[tid + 256] = w21;
        wv[tid]       = again ? fminf(fmaxf(w20, 0.f), 0.1f) : w20;
        wv[tid + 256] = again ? fminf(fmaxf(w21, 0.f), 0.1f) : w21;
        __syncthreads();
        if (!again) break;
    }

    out[(size_t)b * 512 + tid]       = wv[tid];
    out[(size_t)b * 512 + 256 + tid] = wv[tid + 256];
}

extern "C" void kernel_launch(void* const* d_in, const int* in_sizes, int n_in,
                              void* d_out, int out_size, void* d_ws, size_t ws_size,
                              hipStream_t stream) {
    const float* x    = (const float*)d_in[0];
    const float* Wih0 = (const float*)d_in[1];
    const float* Whh0 = (const float*)d_in[2];
    const float* bih0 = (const float*)d_in[3];
    const float* bhh0 = (const float*)d_in[4];
    const float* Wih1 = (const float*)d_in[5];
    const float* Whh1 = (const float*)d_in[6];
    const float* bih1 = (const float*)d_in[7];
    const float* bhh1 = (const float*)d_in[8];
    const float* fcw  = (const float*)d_in[9];
    const float* fcb  = (const float*)d_in[10];
    float* out = (float*)d_out;

    const size_t WHALF = (size_t)G3 * HH;               // 786432
    ushort* W0h = (ushort*)d_ws;
    ushort* W0l = W0h + WHALF;
    ushort* pk  = W0l + WHALF;                          // 1536*3072 ushorts
    float* xi0 = (float*)(pk + (size_t)1536 * 3072);    // [CH][XSLAB]
    float* xi1 = xi0 + (size_t)CH * XSLAB;              // [2][XSLAB]
    float* h0f = xi1 + 2 * (size_t)XSLAB;               // [2][SLAB]
    float* h1f = h0f + 2 * (size_t)SLAB;                // [2][SLAB]
    float* h1n = h1f + 2 * (size_t)SLAB;                // [SLAB]
    ushort* H0h = (ushort*)(h1n + SLAB);                // [2][SLAB] each
    ushort* H0l = H0h + 2 * (size_t)SLAB;
    ushort* H1h = H0l + 2 * (size_t)SLAB;
    ushort* H1l = H1h + 2 * (size_t)SLAB;

    convert_split<<<(G3 * HH) / 1024, 256, 0, stream>>>(Wih0, W0h, W0l, G3 * HH);
    pack_swz<<<1536, 64, 0, stream>>>(Whh0, Wih1, Whh1, pk);
    zero_kernel<<<SLAB / 256, 256, 0, stream>>>(h0f + SLAB, SLAB);
    zero_kernel<<<SLAB / 256, 256, 0, stream>>>(h1f + SLAB, SLAB);
    zero_kernel<<<(SLAB / 2) / 256, 256, 0, stream>>>((float*)(H0h + SLAB), SLAB / 2);
    zero_kernel<<<(SLAB / 2) / 256, 256, 0, stream>>>((float*)(H0l + SLAB), SLAB / 2);
    zero_kernel<<<(SLAB / 2) / 256, 256, 0, stream>>>((float*)(H1h + SLAB), SLAB / 2);
    zero_kernel<<<(SLAB / 2) / 256, 256, 0, stream>>>((float*)(H1l + SLAB), SLAB / 2);

    for (int c = 0; c < TT / CH; ++c) {
        xi_mfma_x<<<dim3(CH * 2, 12), 256, 0, stream>>>(W0h, W0l, x, c * CH, bih0, xi0);
        for (int tl = 0; tl < CH; ++tl) {
            int s = c * CH + tl;
            step_v10<<<768, 512, 0, stream>>>(s, pk, xi0, xi1, bih1, bhh0, bhh1,
                                              h0f, h1f, H0h, H0l, H1h, H1l);
        }
    }
    step_v10<<<768, 512, 0, stream>>>(128, pk, xi0, xi1, bih1, bhh0, bhh1,
                                      h0f, h1f, H0h, H0l, H1h, H1l);
    step_v10<<<768, 512, 0, stream>>>(129, pk, xi0, xi1, bih1, bhh0, bhh1,
                                      h0f, h1f, H0h, H0l, H1h, H1l);

    hT_to_h<<<dim3(8, 4), 256, 0, stream>>>(h1f + SLAB, h1n);
    head_kernel<<<BB, 256, 0, stream>>>(h1n, fcw, fcb, out);
}